// Round 5
// baseline (25.118 us; speedup 1.0000x reference)
//
#include <hip/hip_runtime.h>

// HeightVoxelLoss: B=2, X=200, Y=200, Z=16, C=17, CHOOSE=4000, HEIGHT=16 (h=1)
// loss = mean_b [ sum_valid SmoothL1(w[b,z] * log(softmax(preds)[label] + 1e-3)) / n_valid[b] ]
// w[b,z] = counts>0 ? 3 * (1/3)^(counts/max_count) : 0
//
// 2-dispatch structure, relaxed atomics only (R3 lesson: agent acq_rel per
// block costs >10us on 8-XCD; R4 lesson: relaxed fixed-point int atomics are
// fast and bit-deterministic):
//   A) count_kernel (B,16)x256: ballot counts -> pcnt (non-atomic); zeroes
//      fsum+flag for the next dispatch (stream-ordered).
//   B) loss_kernel (B,250)x256:
//      - cooperative float4 staging of 16 columns (1088B each, 64B-aligned)
//        into LDS; per-voxel LDS reads are 2-way bank-aliased (free);
//      - wave0 computes weights + n_valid from pcnt via 16-lane shuffles,
//        overlapped with staging;
//      - wave shfl_xor reduce (fixed pattern) + 4-way LDS combine -> one
//        relaxed u64 fixed-point atomicAdd per block (order-free, exact);
//      - ticket: fsum add drained by s_waitcnt vmcnt(0), then relaxed flag
//        fetch_add; ticket==last finalizes scalar (reads only integer
//        atomics -> bit-deterministic regardless of which block wins).

namespace {
constexpr int B_ = 2, DX = 200, DY = 200, DZ = 16, DC = 17;
constexpr int CHOOSE_ = 4000, HEIGHT_ = 16;
constexpr int EMPTY_ = 16;
constexpr int CB = 16;                           // count blocks per batch
constexpr int NBLK = (CHOOSE_ * DZ) / 256;       // 250 loss blocks per batch
constexpr float MAXW = 3.0f;
constexpr float LOG2_RATIO = -1.5849625007211562f;  // log2(1/3)
constexpr double SCALE = 16777216.0;                // 2^24 fixed point

struct Ws {
  int pcnt[B_][CB][HEIGHT_];
  unsigned long long fsum[B_];
  int nv[B_];
  unsigned flag;
};
}

__global__ void count_kernel(const int* __restrict__ labels,
                             const int* __restrict__ sel,
                             Ws* __restrict__ ws) {
  __shared__ int s_wcnt[4][HEIGHT_];
  const int b = blockIdx.x;
  const int tid = threadIdx.x;
  const int lane = tid & 63, wv = tid >> 6;
  const int t = blockIdx.y * 256 + tid;

  if (blockIdx.y == 0 && tid == 0) {  // arm accumulators for loss dispatch
    ws->fsum[b] = 0ull;
    if (b == 0) ws->flag = 0u;
  }

  unsigned vm = 0;  // bit z set iff label valid
  if (t < CHOOSE_) {
    const int2 xy = ((const int2*)sel)[b * CHOOSE_ + t];
    const int4* lp = (const int4*)(labels + ((b * DX + xy.x) * DY + xy.y) * DZ);
#pragma unroll
    for (int q = 0; q < 4; ++q) {
      const int4 v = lp[q];
      vm |= (unsigned)(v.x != EMPTY_) << (q * 4 + 0);
      vm |= (unsigned)(v.y != EMPTY_) << (q * 4 + 1);
      vm |= (unsigned)(v.z != EMPTY_) << (q * 4 + 2);
      vm |= (unsigned)(v.w != EMPTY_) << (q * 4 + 3);
    }
  }
#pragma unroll
  for (int z = 0; z < HEIGHT_; ++z) {
    const unsigned long long bal = __ballot((vm >> z) & 1u);
    if (lane == 0) s_wcnt[wv][z] = __popcll(bal);
  }
  __syncthreads();
  if (tid < HEIGHT_)
    ws->pcnt[b][blockIdx.y][tid] =
        s_wcnt[0][tid] + s_wcnt[1][tid] + s_wcnt[2][tid] + s_wcnt[3][tid];
}

__global__ void __launch_bounds__(256) loss_kernel(
    const float* __restrict__ preds, const int* __restrict__ labels,
    const int* __restrict__ sel, Ws* __restrict__ ws,
    float* __restrict__ out) {
  __shared__ float s_p[16][272];  // 16 columns x 272 floats (17408 B)
  __shared__ float s_w[HEIGHT_];
  __shared__ float s_red[4];
  const int b = blockIdx.x;
  const int tid = threadIdx.x;
  const int g = tid >> 4;   // local column 0..15
  const int z = tid & 15;   // z index == lane-in-group

  // Column base (voxel index); byte offset col0*68 is 64B-aligned.
  const int2 xy = ((const int2*)sel)[b * CHOOSE_ + blockIdx.y * 16 + g];
  const int col0 = ((b * DX + xy.x) * DY + xy.y) * DZ;
  const int lab = labels[col0 + z];

  // Cooperative staging: 68 float4 per column, 16 lanes per column.
  const float4* src = (const float4*)(preds + (size_t)col0 * DC);
  float4* dst = (float4*)&s_p[g][0];
#pragma unroll
  for (int k = 0; k < 4; ++k) dst[z + 16 * k] = src[z + 16 * k];
  if (z < 4) dst[z + 64] = src[z + 64];

  // Wave 0 (lanes 0-15): global counts -> weights + n_valid, via shuffles.
  int cc = 0;
  if (tid < 16) {
#pragma unroll
    for (int k = 0; k < CB; ++k) cc += ws->pcnt[b][k][tid];
  }
  if (tid < 64) {  // wave-uniform branch
    int mc = cc, nvs = cc;
#pragma unroll
    for (int m = 1; m < 16; m <<= 1) {
      mc = max(mc, __shfl_xor(mc, m, 16));
      nvs += __shfl_xor(nvs, m, 16);
    }
    if (tid < 16) {
      const float mcf = fmaxf((float)mc, 1.0f);
      s_w[tid] = (cc > 0) ? MAXW * exp2f(LOG2_RATIO * ((float)cc / mcf)) : 0.0f;
    }
    if (tid == 0 && blockIdx.y == 0)
      __hip_atomic_store(&ws->nv[b], nvs, __ATOMIC_RELAXED,
                         __HIP_MEMORY_SCOPE_AGENT);
  }
  __syncthreads();  // s_p and s_w published

  float val = 0.0f;
  if (lab != EMPTY_) {
    const float* pp = &s_p[g][z * DC];  // stride 17 (odd) -> 2-way = free
    float mx = pp[0];
#pragma unroll
    for (int i = 1; i < DC; ++i) mx = fmaxf(mx, pp[i]);
    float se = 0.0f, pl = 0.0f;
#pragma unroll
    for (int i = 0; i < DC; ++i) {
      const float e = expf(pp[i] - mx);
      se += e;
      if (i == lab) pl = e;
    }
    const float wl = s_w[z] * logf(pl / se + 0.001f);
    const float a = fabsf(wl);
    val = (a < 1.0f) ? 0.5f * wl * wl : a - 0.5f;
  }

  // Fixed-pattern wave reduction (deterministic), then 4-way combine.
#pragma unroll
  for (int m = 1; m < 64; m <<= 1) val += __shfl_xor(val, m, 64);
  const int lane = tid & 63, wv = tid >> 6;
  if (lane == 0) s_red[wv] = val;
  __syncthreads();

  if (tid == 0) {
    const float bs = s_red[0] + s_red[1] + s_red[2] + s_red[3];  // fixed order
    const unsigned long long q =
        (unsigned long long)llrint((double)bs * SCALE);
    const unsigned long long old = __hip_atomic_fetch_add(
        &ws->fsum[b], q, __ATOMIC_RELAXED, __HIP_MEMORY_SCOPE_AGENT);
    // Drain the fsum RMW (and the nv store, if any) before taking a ticket:
    // ticket==last then implies every block's integer sum has landed.
    asm volatile("s_waitcnt vmcnt(0)" ::"v"(old) : "memory");
    const unsigned t = __hip_atomic_fetch_add(
        &ws->flag, 1u, __ATOMIC_RELAXED, __HIP_MEMORY_SCOPE_AGENT);
    if (t == (unsigned)(B_ * NBLK - 1)) {
      double total = 0.0;
#pragma unroll
      for (int bb = 0; bb < B_; ++bb) {
        const unsigned long long sv = __hip_atomic_fetch_add(
            &ws->fsum[bb], 0ull, __ATOMIC_RELAXED, __HIP_MEMORY_SCOPE_AGENT);
        const int nv = __hip_atomic_load(&ws->nv[bb], __ATOMIC_RELAXED,
                                         __HIP_MEMORY_SCOPE_AGENT);
        total += ((double)sv / SCALE) / (double)(nv < 1 ? 1 : nv);
      }
      out[0] = (float)(total / (double)B_);
    }
  }
}

extern "C" void kernel_launch(void* const* d_in, const int* in_sizes, int n_in,
                              void* d_out, int out_size, void* d_ws, size_t ws_size,
                              hipStream_t stream) {
  const float* preds = (const float*)d_in[0];
  const int* labels = (const int*)d_in[1];
  const int* sel = (const int*)d_in[2];
  Ws* ws = (Ws*)d_ws;
  float* out = (float*)d_out;

  count_kernel<<<dim3(B_, CB), 256, 0, stream>>>(labels, sel, ws);
  loss_kernel<<<dim3(B_, NBLK), 256, 0, stream>>>(preds, labels, sel, ws, out);
}

// Round 6
// 18.858 us; speedup vs baseline: 1.3319x; 1.3319x over previous
//
#include <hip/hip_runtime.h>

// HeightVoxelLoss: B=2, X=200, Y=200, Z=16, C=17, CHOOSE=4000, HEIGHT=16 (h=1)
// loss = mean_b [ sum_valid SmoothL1(w[b,z] * log(softmax(preds)[label] + 1e-3)) / n_valid[b] ]
// w[b,z] = counts>0 ? 3 * (1/3)^(counts/max_count) : 0
//
// 2-dispatch, single-u64-accumulator design.
// R3 lesson: per-block agent acq_rel fences cost >10us on 8-XCD.
// R5 lesson: per-block DEPENDENT atomic chains (RMW -> wait -> RMW) on one
//   cacheline cost ~7us. Tail must be ONE independent RMW per block.
// Here: block adds (1<<52) | round(block_sum/nv_b * 2^38) to a single u64.
//   Returned old carries BOTH the ticket (top bits) and the running sum --
//   the last block (old>>52 == 499) already holds the grid total in old+q.
//   Integer adds are order-free -> bit-deterministic; out written exactly once.

namespace {
constexpr int B_ = 2, DX = 200, DY = 200, DZ = 16, DC = 17;
constexpr int CHOOSE_ = 4000, HEIGHT_ = 16;
constexpr int EMPTY_ = 16;
constexpr int CB = 16;                          // count blocks per batch
constexpr int NBLK = (CHOOSE_ * DZ) / 256;      // 250 loss blocks per batch
constexpr float MAXW = 3.0f;
constexpr float LOG2_RATIO = -1.5849625007211562f;  // log2(1/3)
constexpr double QS = 274877906944.0;               // 2^38 fixed point
constexpr unsigned long long TICKET = 1ull << 52;
constexpr unsigned long long QMASK = TICKET - 1ull;

struct Ws {
  int pcnt[B_][CB][HEIGHT_];            // 2048 B, read-only during loss
  alignas(128) unsigned long long acc;  // own cache line
};
}

__global__ void count_kernel(const int* __restrict__ labels,
                             const int* __restrict__ sel,
                             Ws* __restrict__ ws) {
  __shared__ int s_wcnt[4][HEIGHT_];
  const int b = blockIdx.x;
  const int tid = threadIdx.x;
  const int lane = tid & 63, wv = tid >> 6;
  const int t = blockIdx.y * 256 + tid;

  if (b == 0 && blockIdx.y == 0 && tid == 0) ws->acc = 0ull;  // re-arm per run

  unsigned vm = 0;  // bit z set iff label valid
  if (t < CHOOSE_) {
    const int2 xy = ((const int2*)sel)[b * CHOOSE_ + t];
    const int4* lp = (const int4*)(labels + ((b * DX + xy.x) * DY + xy.y) * DZ);
#pragma unroll
    for (int q = 0; q < 4; ++q) {
      const int4 v = lp[q];
      vm |= (unsigned)(v.x != EMPTY_) << (q * 4 + 0);
      vm |= (unsigned)(v.y != EMPTY_) << (q * 4 + 1);
      vm |= (unsigned)(v.z != EMPTY_) << (q * 4 + 2);
      vm |= (unsigned)(v.w != EMPTY_) << (q * 4 + 3);
    }
  }
#pragma unroll
  for (int z = 0; z < HEIGHT_; ++z) {
    const unsigned long long bal = __ballot((vm >> z) & 1u);
    if (lane == 0) s_wcnt[wv][z] = __popcll(bal);
  }
  __syncthreads();
  if (tid < HEIGHT_)
    ws->pcnt[b][blockIdx.y][tid] =
        s_wcnt[0][tid] + s_wcnt[1][tid] + s_wcnt[2][tid] + s_wcnt[3][tid];
}

__global__ void __launch_bounds__(256) loss_kernel(
    const float* __restrict__ preds, const int* __restrict__ labels,
    const int* __restrict__ sel, Ws* __restrict__ ws,
    float* __restrict__ out) {
  __shared__ float s_p[16][272];  // 16 columns x 272 floats (17408 B)
  __shared__ float s_w[HEIGHT_];
  __shared__ float s_red[4];
  const int b = blockIdx.x;
  const int tid = threadIdx.x;
  const int g = tid >> 4;   // local column 0..15
  const int z = tid & 15;   // voxel z == lane-in-group

  // Column base (voxel index); byte offset col0*68 is 64B-aligned.
  const int2 xy = ((const int2*)sel)[b * CHOOSE_ + blockIdx.y * 16 + g];
  const int col0 = ((b * DX + xy.x) * DY + xy.y) * DZ;
  const int lab = labels[col0 + z];

  // Cooperative staging: 68 float4 per column, 16 lanes per column.
  const float4* src = (const float4*)(preds + (size_t)col0 * DC);
  float4* dst = (float4*)&s_p[g][0];
#pragma unroll
  for (int k = 0; k < 4; ++k) dst[z + 16 * k] = src[z + 16 * k];
  if (z < 4) dst[z + 64] = src[z + 64];

  // Wave 0 (lanes 0-15): global counts -> weights + n_valid, via shuffles,
  // overlapped with the staging loads above.
  int nv_b = 1;
  if (tid < 64) {  // wave-uniform branch
    int cc = 0;
    if (tid < 16) {
#pragma unroll
      for (int k = 0; k < CB; ++k) cc += ws->pcnt[b][k][tid];
    }
    int mc = cc, nvs = cc;
#pragma unroll
    for (int m = 1; m < 16; m <<= 1) {
      mc = max(mc, __shfl_xor(mc, m, 16));
      nvs += __shfl_xor(nvs, m, 16);
    }
    if (tid < 16) {
      const float mcf = fmaxf((float)mc, 1.0f);
      s_w[tid] = (cc > 0) ? MAXW * exp2f(LOG2_RATIO * ((float)cc / mcf)) : 0.0f;
    }
    nv_b = nvs < 1 ? 1 : nvs;
  }
  __syncthreads();  // s_p and s_w published

  float val = 0.0f;
  if (lab != EMPTY_) {
    const float* pp = &s_p[g][z * DC];  // stride 17 (odd) -> 2-way = free
    float mx = pp[0];
#pragma unroll
    for (int i = 1; i < DC; ++i) mx = fmaxf(mx, pp[i]);
    float se = 0.0f, pl = 0.0f;
#pragma unroll
    for (int i = 0; i < DC; ++i) {
      const float e = expf(pp[i] - mx);
      se += e;
      if (i == lab) pl = e;
    }
    const float wl = s_w[z] * logf(pl / se + 0.001f);
    const float a = fabsf(wl);
    val = (a < 1.0f) ? 0.5f * wl * wl : a - 0.5f;
  }

  // Fixed-pattern wave reduction (deterministic), then 4-way combine.
#pragma unroll
  for (int m = 1; m < 64; m <<= 1) val += __shfl_xor(val, m, 64);
  if ((tid & 63) == 0) s_red[tid >> 6] = val;
  __syncthreads();

  if (tid == 0) {
    const float bs = s_red[0] + s_red[1] + s_red[2] + s_red[3];  // fixed order
    // Per-block contribution, pre-divided by this batch's n_valid, quantized.
    // Grid total <= ~20.7 * 2^38 < 2^43 << 2^52: no carry into ticket field.
    const unsigned long long q =
        (unsigned long long)llrint((double)bs / (double)nv_b * QS) + TICKET;
    const unsigned long long old = __hip_atomic_fetch_add(
        &ws->acc, q, __ATOMIC_RELAXED, __HIP_MEMORY_SCOPE_AGENT);
    if ((old >> 52) == (unsigned long long)(B_ * NBLK - 1)) {
      // Last block: old+q already contains every block's contribution.
      const double total = (double)((old + q) & QMASK) / QS;
      out[0] = (float)(total / (double)B_);
    }
  }
}

extern "C" void kernel_launch(void* const* d_in, const int* in_sizes, int n_in,
                              void* d_out, int out_size, void* d_ws, size_t ws_size,
                              hipStream_t stream) {
  const float* preds = (const float*)d_in[0];
  const int* labels = (const int*)d_in[1];
  const int* sel = (const int*)d_in[2];
  Ws* ws = (Ws*)d_ws;
  float* out = (float*)d_out;

  count_kernel<<<dim3(B_, CB), 256, 0, stream>>>(labels, sel, ws);
  loss_kernel<<<dim3(B_, NBLK), 256, 0, stream>>>(preds, labels, sel, ws, out);
}